// Round 1
// 936.320 us; speedup vs baseline: 1.1341x; 1.1341x over previous
//
#include <hip/hip_runtime.h>

#define T 8192
#define D 1024
#define E 64
#define CAP 256

static const size_t TEC = (size_t)T * E * CAP;       // 134217728
#define C_OFF   ((size_t)1)
#define M_OFF   ((size_t)1 + (size_t)T * E * CAP)
#define CNT_OFF ((size_t)1 + 2 * (size_t)T * E * CAP)

// K1: one wave per token. red = x_row @ W_red (wave-reduced), logits vs
// normalized centroids (lane = expert), softmax + first-index argmax.
// Accumulates Sg[e] = sum_t gates[t,e] via LDS partials -> global atomics.
__global__ __launch_bounds__(256) void k1_gate(
    const float* __restrict__ x, const float* __restrict__ Wred,
    const float* __restrict__ cent, int* __restrict__ idx1,
    float* __restrict__ g15, float* __restrict__ Sg)
{
    __shared__ float wcol[4 * D];   // column-major: wcol[c*D + d], bank = d%32 (2-way, free)
    __shared__ float cn[E * 4];
    __shared__ float sg[E];
    const int tid = threadIdx.x;

    for (int i = tid; i < 4 * D; i += 256) {
        int d = i >> 2, c = i & 3;
        wcol[c * D + d] = Wred[i];
    }
    if (tid < E) {
        float c0 = cent[tid * 4 + 0];
        float c1 = cent[tid * 4 + 1];
        float c2 = cent[tid * 4 + 2];
        float c3 = cent[tid * 4 + 3];
        float n = fmaxf(sqrtf(c0 * c0 + c1 * c1 + c2 * c2 + c3 * c3), 1e-4f);
        cn[tid * 4 + 0] = c0 / n;
        cn[tid * 4 + 1] = c1 / n;
        cn[tid * 4 + 2] = c2 / n;
        cn[tid * 4 + 3] = c3 / n;
        sg[tid] = 0.0f;
    }
    __syncthreads();

    const int wave = tid >> 6, lane = tid & 63;
    for (int it = 0; it < 4; ++it) {               // 512 blocks * 4 iters * 4 waves = 8192 tokens
        const int t = blockIdx.x * 16 + it * 4 + wave;
        const float* xr = x + (size_t)t * D;
        float a0 = 0.f, a1 = 0.f, a2 = 0.f, a3 = 0.f;
        #pragma unroll
        for (int k = 0; k < 16; ++k) {
            int d = k * 64 + lane;                 // coalesced 4B/lane
            float xv = xr[d];
            a0 += xv * wcol[d];
            a1 += xv * wcol[D + d];
            a2 += xv * wcol[2 * D + d];
            a3 += xv * wcol[3 * D + d];
        }
        #pragma unroll
        for (int off = 32; off; off >>= 1) {       // xor-butterfly: all lanes get full sums
            a0 += __shfl_xor(a0, off);
            a1 += __shfl_xor(a1, off);
            a2 += __shfl_xor(a2, off);
            a3 += __shfl_xor(a3, off);
        }
        // lane e's logit = red . cn[e]
        float logit = a0 * cn[lane * 4 + 0] + a1 * cn[lane * 4 + 1]
                    + a2 * cn[lane * 4 + 2] + a3 * cn[lane * 4 + 3];
        float m = logit;
        #pragma unroll
        for (int off = 32; off; off >>= 1) m = fmaxf(m, __shfl_xor(m, off));
        unsigned long long ball = __ballot(logit == m);
        int amax = __ffsll(ball) - 1;              // first-occurrence argmax (matches jnp)
        float ev = expf(logit - m);
        float s = ev;
        #pragma unroll
        for (int off = 32; off; off >>= 1) s += __shfl_xor(s, off);
        atomicAdd(&sg[lane], ev / s);              // Sg partial, distinct addr per lane
        if (lane == 0) { idx1[t] = amax; g15[t] = 1.5f / s; }  // gate at argmax = 1/s
    }
    __syncthreads();
    if (tid < E) atomicAdd(&Sg[tid], sg[tid]);
}

// K2: per-256-token-chunk expert histogram (32 chunks).
__global__ __launch_bounds__(256) void k2_hist(const int* __restrict__ idx1,
                                               int* __restrict__ bc)
{
    __shared__ int h[E];
    const int tid = threadIdx.x;
    if (tid < E) h[tid] = 0;
    __syncthreads();
    atomicAdd(&h[idx1[blockIdx.x * 256 + tid]], 1);
    __syncthreads();
    if (tid < E) bc[blockIdx.x * E + tid] = h[tid];
}

// K3: one wave. Exclusive prefix over chunks per expert, total counts,
// l_aux = E * sum_e Sg[e]*cnt[e] / T^2.
__global__ __launch_bounds__(64) void k3_prefix(const int* __restrict__ bc,
                                                int* __restrict__ pf,
                                                const float* __restrict__ Sg,
                                                float* __restrict__ out)
{
    const int e = threadIdx.x;   // 64 threads = 64 experts
    int run = 0;
    for (int b = 0; b < 32; ++b) {
        pf[b * E + e] = run;
        run += bc[b * E + e];
    }
    out[CNT_OFF + e] = (float)run;                 // expert_counts (pre-capacity)
    float v = Sg[e] * (float)run;
    #pragma unroll
    for (int off = 32; off; off >>= 1) v += __shfl_xor(v, off);
    if (e == 0) out[0] = v * ((float)E / ((float)T * (float)T));  // 64/2^26 exact
}

// K4: scatter the nonzeros. Within-chunk rank via LDS broadcast scan.
__global__ __launch_bounds__(256) void k4_scatter(const int* __restrict__ idx1,
                                                  const float* __restrict__ g15,
                                                  const int* __restrict__ pf,
                                                  float* __restrict__ out)
{
    __shared__ int ids[256];
    const int tid = threadIdx.x;
    const int t = blockIdx.x * 256 + tid;
    const int e = idx1[t];
    ids[tid] = e;
    __syncthreads();
    int r = 0;
    for (int j = 0; j < 256; ++j)                  // uniform loop, LDS broadcast read
        r += (j < tid && ids[j] == e) ? 1 : 0;
    const int rank = pf[blockIdx.x * E + e] + r;   // token's position within its expert
    if (rank < CAP) {
        size_t off = (size_t)t * (E * CAP) + (size_t)e * CAP + rank;
        out[C_OFF + off] = g15[t];                 // combine value (1.5 * max gate, > 0)
        out[M_OFF + off] = 1.0f;                   // dispatch_mask
    }
}

extern "C" void kernel_launch(void* const* d_in, const int* in_sizes, int n_in,
                              void* d_out, int out_size, void* d_ws, size_t ws_size,
                              hipStream_t stream)
{
    const float* x    = (const float*)d_in[0];   // [T, D]
    const float* Wred = (const float*)d_in[1];   // [D, 4]
    const float* cent = (const float*)d_in[2];   // [E, 4]
    float* out = (float*)d_out;

    char* ws = (char*)d_ws;                      // ~82 KB used
    int*   idx1 = (int*)ws;                      // T ints
    float* g15  = (float*)(ws + 32768);          // T floats
    float* Sg   = (float*)(ws + 65536);          // 64 floats (needs zeroing)
    int*   bc   = (int*)(ws + 65536 + 256);      // 32*64 ints
    int*   pf   = (int*)(ws + 65536 + 256 + 8192);

    // Zero the poisoned output. out_size is in BYTES (rocprof evidence: the
    // old out_size*sizeof(float) memset wrote 4,194,304 KB = 4 GiB = 4x the
    // 1.0737 GB logical output, at 6.27 TB/s for 685 us). Zeroing exactly
    // out_size bytes covers the full declared output and cuts the fill 4x.
    hipMemsetAsync(d_out, 0, (size_t)out_size, stream);
    hipMemsetAsync(Sg, 0, E * sizeof(float), stream);

    k1_gate<<<512, 256, 0, stream>>>(x, Wred, cent, idx1, g15, Sg);
    k2_hist<<<32, 256, 0, stream>>>(idx1, bc);
    k3_prefix<<<1, 64, 0, stream>>>(bc, pf, Sg, out);
    k4_scatter<<<32, 256, 0, stream>>>(idx1, g15, pf, out);
}